// Round 2
// baseline (1156.623 us; speedup 1.0000x reference)
//
#include <hip/hip_runtime.h>
#include <math.h>

#define TN 64

__device__ __forceinline__ float sigmoidf_(float v) {
    return 1.f / (1.f + __expf(-v));
}

template <typename StoreF>
__device__ __forceinline__ void gemm_tile(
    const float* __restrict__ W, const float xs[TN][132],
    int ri, int ci, StoreF store)
{
    float acc[8][4];
    #pragma unroll
    for (int j = 0; j < 8; ++j)
        acc[j][0] = acc[j][1] = acc[j][2] = acc[j][3] = 0.f;
    #pragma unroll 4
    for (int k = 0; k < 128; ++k) {
        const float4 wv = *(const float4*)(W + k * 128 + ci);
        #pragma unroll
        for (int j = 0; j < 8; ++j) {
            const float xv = xs[ri + j][k];
            acc[j][0] = fmaf(xv, wv.x, acc[j][0]);
            acc[j][1] = fmaf(xv, wv.y, acc[j][1]);
            acc[j][2] = fmaf(xv, wv.z, acc[j][2]);
            acc[j][3] = fmaf(xv, wv.w, acc[j][3]);
        }
    }
    #pragma unroll
    for (int j = 0; j < 8; ++j)
        store(j, acc[j][0], acc[j][1], acc[j][2], acc[j][3]);
}

// Phase 1: per-node transforms.
//   h_in  = x @ W_in          [N,128]
//   h_out = x @ W_out         [N,128]
//   sg_in[n][l]  = sigmoid(x[n]@W_in_g  + b_in_g[l])
//   sg_out[n][l] = sigmoid(x[n]@W_out_g + b_out_g[l])
//   out   = sigmoid(x@W_loop_g + b_loop_g) * (x@W_loop + b_loop)   (accumulator init)
__global__ __launch_bounds__(256) void sgcn_node(
    const float* __restrict__ x,
    const float* __restrict__ W_loop, const float* __restrict__ b_loop,
    const float* __restrict__ W_loop_g, const float* __restrict__ b_loop_g,
    const float* __restrict__ W_in, const float* __restrict__ W_in_g, const float* __restrict__ b_in_g,
    const float* __restrict__ W_out, const float* __restrict__ W_out_g, const float* __restrict__ b_out_g,
    float* __restrict__ h_in, float* __restrict__ h_out,
    float* __restrict__ sg_in, float* __restrict__ sg_out,
    float* __restrict__ out, int N)
{
    __shared__ float xs[TN][132];   // +4 pad keeps 16B alignment, breaks pow2 stride
    __shared__ float gls[TN];
    const int tid = threadIdx.x;
    const int n0 = blockIdx.x * TN;

    // stage x tile [TN][128]
    for (int i = tid * 4; i < TN * 128; i += 256 * 4) {
        const int row = i >> 7;
        const int col = i & 127;
        float4 v = make_float4(0.f, 0.f, 0.f, 0.f);
        if (n0 + row < N) v = *(const float4*)(x + (size_t)(n0 + row) * 128 + col);
        *(float4*)&xs[row][col] = v;
    }
    __syncthreads();

    // gate logits (3 dot products per node), one thread per node
    if (tid < TN) {
        float gl = 0.f, gi = 0.f, go = 0.f;
        #pragma unroll 4
        for (int k = 0; k < 128; ++k) {
            const float xv = xs[tid][k];
            gl = fmaf(xv, W_loop_g[k], gl);
            gi = fmaf(xv, W_in_g[k], gi);
            go = fmaf(xv, W_out_g[k], go);
        }
        gls[tid] = sigmoidf_(gl + b_loop_g[0]);
        const int n = n0 + tid;
        if (n < N) {
            #pragma unroll
            for (int l = 0; l < 4; ++l) {
                sg_in[(size_t)n * 4 + l]  = sigmoidf_(gi + b_in_g[l]);
                sg_out[(size_t)n * 4 + l] = sigmoidf_(go + b_out_g[l]);
            }
        }
    }
    __syncthreads();

    const int ci = (tid & 31) * 4;   // output col base (0..124)
    const int ri = (tid >> 5) * 8;   // node base within tile (0..56)

    // h_in = x @ W_in
    gemm_tile(W_in, xs, ri, ci,
        [&](int j, float a0, float a1, float a2, float a3) {
            const int n = n0 + ri + j;
            if (n < N)
                *(float4*)(h_in + (size_t)n * 128 + ci) = make_float4(a0, a1, a2, a3);
        });

    // h_out = x @ W_out
    gemm_tile(W_out, xs, ri, ci,
        [&](int j, float a0, float a1, float a2, float a3) {
            const int n = n0 + ri + j;
            if (n < N)
                *(float4*)(h_out + (size_t)n * 128 + ci) = make_float4(a0, a1, a2, a3);
        });

    // out = gated self-loop (accumulator init)
    {
        const float4 bl = *(const float4*)(b_loop + ci);
        gemm_tile(W_loop, xs, ri, ci,
            [&](int j, float a0, float a1, float a2, float a3) {
                const int n = n0 + ri + j;
                if (n < N) {
                    const float g = gls[ri + j];
                    *(float4*)(out + (size_t)n * 128 + ci) =
                        make_float4(g * (a0 + bl.x), g * (a1 + bl.y),
                                    g * (a2 + bl.z), g * (a3 + bl.w));
                }
            });
    }
}

// Phase 2: edge scatter. One wave (64 lanes) per edge; float2 per lane covers 128 cols.
__global__ __launch_bounds__(256) void sgcn_scatter(
    const float* __restrict__ h_in, const float* __restrict__ h_out,
    const float* __restrict__ sg_in, const float* __restrict__ sg_out,
    const int* __restrict__ ei,   // [2,E]
    const int* __restrict__ lab,  // [E]
    const float* __restrict__ b_in,   // [4,128]
    const float* __restrict__ b_out,  // [4,128]
    float* __restrict__ out, int E)
{
    const int lane = threadIdx.x & 63;
    const int wid = (blockIdx.x * blockDim.x + threadIdx.x) >> 6;
    const int nw = (gridDim.x * blockDim.x) >> 6;
    const int c = lane * 2;

    for (int e = wid; e < E; e += nw) {
        const int s = ei[e];
        const int d = ei[E + e];
        const int l = lab[e];

        // in-direction: gather h_in[s], scatter to out[d]
        {
            const float2 hv = *(const float2*)(h_in + (size_t)s * 128 + c);
            const float2 bv = *(const float2*)(b_in + l * 128 + c);
            const float g = sg_in[(size_t)s * 4 + l];
            atomicAdd(out + (size_t)d * 128 + c,     g * (hv.x + bv.x));
            atomicAdd(out + (size_t)d * 128 + c + 1, g * (hv.y + bv.y));
        }
        // out-direction (flipped): gather h_out[d], scatter to out[s]
        {
            const float2 hv = *(const float2*)(h_out + (size_t)d * 128 + c);
            const float2 bv = *(const float2*)(b_out + l * 128 + c);
            const float g = sg_out[(size_t)d * 4 + l];
            atomicAdd(out + (size_t)s * 128 + c,     g * (hv.x + bv.x));
            atomicAdd(out + (size_t)s * 128 + c + 1, g * (hv.y + bv.y));
        }
    }
}

// Phase 3: ReLU in place.
__global__ __launch_bounds__(256) void sgcn_relu(float* __restrict__ out, long total4)
{
    const long i = (long)blockIdx.x * blockDim.x + threadIdx.x;
    if (i < total4) {
        float4 v = ((float4*)out)[i];
        v.x = fmaxf(v.x, 0.f); v.y = fmaxf(v.y, 0.f);
        v.z = fmaxf(v.z, 0.f); v.w = fmaxf(v.w, 0.f);
        ((float4*)out)[i] = v;
    }
}

extern "C" void kernel_launch(void* const* d_in, const int* in_sizes, int n_in,
                              void* d_out, int out_size, void* d_ws, size_t ws_size,
                              hipStream_t stream)
{
    const float* x        = (const float*)d_in[0];
    const int*   ei       = (const int*)d_in[1];
    const int*   lab      = (const int*)d_in[2];
    const float* W_loop   = (const float*)d_in[3];
    const float* b_loop   = (const float*)d_in[4];
    const float* W_loop_g = (const float*)d_in[5];
    const float* b_loop_g = (const float*)d_in[6];
    const float* W_in     = (const float*)d_in[7];
    const float* b_in     = (const float*)d_in[8];
    const float* W_in_g   = (const float*)d_in[9];
    const float* b_in_g   = (const float*)d_in[10];
    const float* W_out    = (const float*)d_in[11];
    const float* b_out    = (const float*)d_in[12];
    const float* W_out_g  = (const float*)d_in[13];
    const float* b_out_g  = (const float*)d_in[14];

    const int N = in_sizes[0] / 128;
    const int E = in_sizes[1] / 2;

    float* h_in   = (float*)d_ws;
    float* h_out  = h_in  + (size_t)N * 128;
    float* sg_in  = h_out + (size_t)N * 128;
    float* sg_out = sg_in + (size_t)N * 4;

    float* out = (float*)d_out;

    dim3 blk(256);
    sgcn_node<<<dim3((N + TN - 1) / TN), blk, 0, stream>>>(
        x, W_loop, b_loop, W_loop_g, b_loop_g,
        W_in, W_in_g, b_in_g, W_out, W_out_g, b_out_g,
        h_in, h_out, sg_in, sg_out, out, N);

    sgcn_scatter<<<dim3(2048), blk, 0, stream>>>(
        h_in, h_out, sg_in, sg_out, ei, lab, b_in, b_out, out, E);

    const long total4 = (long)N * 128 / 4;
    sgcn_relu<<<dim3((unsigned)((total4 + 255) / 256)), blk, 0, stream>>>(out, total4);
}

// Round 3
// 667.479 us; speedup vs baseline: 1.7328x; 1.7328x over previous
//
#include <hip/hip_runtime.h>
#include <math.h>

#define TN 64

__device__ __forceinline__ float sigmoidf_(float v) {
    return 1.f / (1.f + __expf(-v));
}

template <typename StoreF>
__device__ __forceinline__ void gemm_tile(
    const float* __restrict__ W, const float xs[TN][132],
    int ri, int ci, StoreF store)
{
    float acc[8][4];
    #pragma unroll
    for (int j = 0; j < 8; ++j)
        acc[j][0] = acc[j][1] = acc[j][2] = acc[j][3] = 0.f;
    #pragma unroll 4
    for (int k = 0; k < 128; ++k) {
        const float4 wv = *(const float4*)(W + k * 128 + ci);
        #pragma unroll
        for (int j = 0; j < 8; ++j) {
            const float xv = xs[ri + j][k];
            acc[j][0] = fmaf(xv, wv.x, acc[j][0]);
            acc[j][1] = fmaf(xv, wv.y, acc[j][1]);
            acc[j][2] = fmaf(xv, wv.z, acc[j][2]);
            acc[j][3] = fmaf(xv, wv.w, acc[j][3]);
        }
    }
    #pragma unroll
    for (int j = 0; j < 8; ++j)
        store(j, acc[j][0], acc[j][1], acc[j][2], acc[j][3]);
}

// Phase 1: per-node transforms (h_in, h_out, gates, x_loop into out).
__global__ __launch_bounds__(256) void sgcn_node(
    const float* __restrict__ x,
    const float* __restrict__ W_loop, const float* __restrict__ b_loop,
    const float* __restrict__ W_loop_g, const float* __restrict__ b_loop_g,
    const float* __restrict__ W_in, const float* __restrict__ W_in_g, const float* __restrict__ b_in_g,
    const float* __restrict__ W_out, const float* __restrict__ W_out_g, const float* __restrict__ b_out_g,
    float* __restrict__ h_in, float* __restrict__ h_out,
    float* __restrict__ sg_in, float* __restrict__ sg_out,
    float* __restrict__ out, int N)
{
    __shared__ float xs[TN][132];
    __shared__ float gls[TN];
    const int tid = threadIdx.x;
    const int n0 = blockIdx.x * TN;

    for (int i = tid * 4; i < TN * 128; i += 256 * 4) {
        const int row = i >> 7;
        const int col = i & 127;
        float4 v = make_float4(0.f, 0.f, 0.f, 0.f);
        if (n0 + row < N) v = *(const float4*)(x + (size_t)(n0 + row) * 128 + col);
        *(float4*)&xs[row][col] = v;
    }
    __syncthreads();

    if (tid < TN) {
        float gl = 0.f, gi = 0.f, go = 0.f;
        #pragma unroll 4
        for (int k = 0; k < 128; ++k) {
            const float xv = xs[tid][k];
            gl = fmaf(xv, W_loop_g[k], gl);
            gi = fmaf(xv, W_in_g[k], gi);
            go = fmaf(xv, W_out_g[k], go);
        }
        gls[tid] = sigmoidf_(gl + b_loop_g[0]);
        const int n = n0 + tid;
        if (n < N) {
            #pragma unroll
            for (int l = 0; l < 4; ++l) {
                sg_in[(size_t)n * 4 + l]  = sigmoidf_(gi + b_in_g[l]);
                sg_out[(size_t)n * 4 + l] = sigmoidf_(go + b_out_g[l]);
            }
        }
    }
    __syncthreads();

    const int ci = (tid & 31) * 4;
    const int ri = (tid >> 5) * 8;

    gemm_tile(W_in, xs, ri, ci,
        [&](int j, float a0, float a1, float a2, float a3) {
            const int n = n0 + ri + j;
            if (n < N)
                *(float4*)(h_in + (size_t)n * 128 + ci) = make_float4(a0, a1, a2, a3);
        });

    gemm_tile(W_out, xs, ri, ci,
        [&](int j, float a0, float a1, float a2, float a3) {
            const int n = n0 + ri + j;
            if (n < N)
                *(float4*)(h_out + (size_t)n * 128 + ci) = make_float4(a0, a1, a2, a3);
        });

    {
        const float4 bl = *(const float4*)(b_loop + ci);
        gemm_tile(W_loop, xs, ri, ci,
            [&](int j, float a0, float a1, float a2, float a3) {
                const int n = n0 + ri + j;
                if (n < N) {
                    const float g = gls[ri + j];
                    *(float4*)(out + (size_t)n * 128 + ci) =
                        make_float4(g * (a0 + bl.x), g * (a1 + bl.y),
                                    g * (a2 + bl.z), g * (a3 + bl.w));
                }
            });
    }
}

// ---------- CSR build ----------
__global__ __launch_bounds__(256) void sgcn_zero(int* __restrict__ p, int n)
{
    const int i = blockIdx.x * blockDim.x + threadIdx.x;
    if (i < n) p[i] = 0;
}

__global__ __launch_bounds__(256) void sgcn_hist(
    const int* __restrict__ ei, int* __restrict__ cnt_in, int* __restrict__ cnt_out, int E)
{
    const int e = blockIdx.x * blockDim.x + threadIdx.x;
    if (e < E) {
        atomicAdd(cnt_in + ei[E + e], 1);   // in-direction keyed by dst
        atomicAdd(cnt_out + ei[e], 1);      // out-direction keyed by src
    }
}

// blockIdx 0 -> (fill_in,row_in), 1 -> (fill_out,row_out). fill holds counts in,
// start positions out; row gets exclusive prefix + row[N] = total.
__global__ __launch_bounds__(1024) void sgcn_scan(
    int* __restrict__ fill_in, int* __restrict__ row_in,
    int* __restrict__ fill_out, int* __restrict__ row_out, int N)
{
    int* fill = blockIdx.x ? fill_out : fill_in;
    int* row  = blockIdx.x ? row_out  : row_in;
    __shared__ int part[1024];
    const int t = threadIdx.x;
    const int chunk = (N + 1023) >> 10;
    const int lo = t * chunk;
    const int hi = min(lo + chunk, N);
    int sum = 0;
    for (int i = lo; i < hi; ++i) sum += fill[i];
    part[t] = sum;
    __syncthreads();
    for (int off = 1; off < 1024; off <<= 1) {
        int v = (t >= off) ? part[t - off] : 0;
        __syncthreads();
        part[t] += v;
        __syncthreads();
    }
    int run = (t > 0) ? part[t - 1] : 0;
    for (int i = lo; i < hi; ++i) {
        const int cnt = fill[i];
        row[i] = run;
        fill[i] = run;
        run += cnt;
    }
    if (t == 1023) row[N] = part[1023];
}

__global__ __launch_bounds__(256) void sgcn_fill(
    const int* __restrict__ ei, const int* __restrict__ lab,
    int* __restrict__ fill_in, int* __restrict__ idx_in,
    int* __restrict__ fill_out, int* __restrict__ idx_out, int E)
{
    const int e = blockIdx.x * blockDim.x + threadIdx.x;
    if (e < E) {
        const int s = ei[e];
        const int d = ei[E + e];
        const int l = lab[e];
        const int pi = atomicAdd(fill_in + d, 1);
        idx_in[pi] = s * 4 + l;                 // p>>2 = src node, p&3 = label
        const int po = atomicAdd(fill_out + s, 1);
        idx_out[po] = d * 4 + l;
    }
}

// Phase 2 (CSR): one wave per node; gather both directions, add self-loop (in out),
// relu, store. No atomics.
__global__ __launch_bounds__(256) void sgcn_gather(
    const float* __restrict__ h_in, const float* __restrict__ h_out,
    const float* __restrict__ sg_in, const float* __restrict__ sg_out,
    const int* __restrict__ row_in, const int* __restrict__ idx_in,
    const int* __restrict__ row_out, const int* __restrict__ idx_out,
    const float* __restrict__ b_in, const float* __restrict__ b_out,
    float* __restrict__ out, int N)
{
    const int lane = threadIdx.x & 63;
    const int node = (int)((blockIdx.x * (unsigned)blockDim.x + threadIdx.x) >> 6);
    if (node >= N) return;
    const int c = lane * 2;

    float2 acc = *(const float2*)(out + (size_t)node * 128 + c);

    int e0 = row_in[node], e1 = row_in[node + 1];
    for (int e = e0; e < e1; ++e) {
        const int p = idx_in[e];
        const float g = sg_in[p];
        const float2 hv = *(const float2*)(h_in + (size_t)(p >> 2) * 128 + c);
        const float2 bv = *(const float2*)(b_in + (p & 3) * 128 + c);
        acc.x = fmaf(g, hv.x + bv.x, acc.x);
        acc.y = fmaf(g, hv.y + bv.y, acc.y);
    }
    e0 = row_out[node]; e1 = row_out[node + 1];
    for (int e = e0; e < e1; ++e) {
        const int p = idx_out[e];
        const float g = sg_out[p];
        const float2 hv = *(const float2*)(h_out + (size_t)(p >> 2) * 128 + c);
        const float2 bv = *(const float2*)(b_out + (p & 3) * 128 + c);
        acc.x = fmaf(g, hv.x + bv.x, acc.x);
        acc.y = fmaf(g, hv.y + bv.y, acc.y);
    }
    *(float2*)(out + (size_t)node * 128 + c) =
        make_float2(fmaxf(acc.x, 0.f), fmaxf(acc.y, 0.f));
}

// ---------- fallback (round-2 proven path) ----------
__global__ __launch_bounds__(256) void sgcn_scatter(
    const float* __restrict__ h_in, const float* __restrict__ h_out,
    const float* __restrict__ sg_in, const float* __restrict__ sg_out,
    const int* __restrict__ ei, const int* __restrict__ lab,
    const float* __restrict__ b_in, const float* __restrict__ b_out,
    float* __restrict__ out, int E)
{
    const int lane = threadIdx.x & 63;
    const int wid = (blockIdx.x * blockDim.x + threadIdx.x) >> 6;
    const int nw = (gridDim.x * blockDim.x) >> 6;
    const int c = lane * 2;

    for (int e = wid; e < E; e += nw) {
        const int s = ei[e];
        const int d = ei[E + e];
        const int l = lab[e];
        {
            const float2 hv = *(const float2*)(h_in + (size_t)s * 128 + c);
            const float2 bv = *(const float2*)(b_in + l * 128 + c);
            const float g = sg_in[(size_t)s * 4 + l];
            atomicAdd(out + (size_t)d * 128 + c,     g * (hv.x + bv.x));
            atomicAdd(out + (size_t)d * 128 + c + 1, g * (hv.y + bv.y));
        }
        {
            const float2 hv = *(const float2*)(h_out + (size_t)d * 128 + c);
            const float2 bv = *(const float2*)(b_out + l * 128 + c);
            const float g = sg_out[(size_t)d * 4 + l];
            atomicAdd(out + (size_t)s * 128 + c,     g * (hv.x + bv.x));
            atomicAdd(out + (size_t)s * 128 + c + 1, g * (hv.y + bv.y));
        }
    }
}

__global__ __launch_bounds__(256) void sgcn_relu(float* __restrict__ out, long total4)
{
    const long i = (long)blockIdx.x * blockDim.x + threadIdx.x;
    if (i < total4) {
        float4 v = ((float4*)out)[i];
        v.x = fmaxf(v.x, 0.f); v.y = fmaxf(v.y, 0.f);
        v.z = fmaxf(v.z, 0.f); v.w = fmaxf(v.w, 0.f);
        ((float4*)out)[i] = v;
    }
}

extern "C" void kernel_launch(void* const* d_in, const int* in_sizes, int n_in,
                              void* d_out, int out_size, void* d_ws, size_t ws_size,
                              hipStream_t stream)
{
    const float* x        = (const float*)d_in[0];
    const int*   ei       = (const int*)d_in[1];
    const int*   lab      = (const int*)d_in[2];
    const float* W_loop   = (const float*)d_in[3];
    const float* b_loop   = (const float*)d_in[4];
    const float* W_loop_g = (const float*)d_in[5];
    const float* b_loop_g = (const float*)d_in[6];
    const float* W_in     = (const float*)d_in[7];
    const float* b_in     = (const float*)d_in[8];
    const float* W_in_g   = (const float*)d_in[9];
    const float* b_in_g   = (const float*)d_in[10];
    const float* W_out    = (const float*)d_in[11];
    const float* b_out    = (const float*)d_in[12];
    const float* W_out_g  = (const float*)d_in[13];
    const float* b_out_g  = (const float*)d_in[14];

    const int N = in_sizes[0] / 128;
    const int E = in_sizes[1] / 2;

    float* h_in   = (float*)d_ws;
    float* h_out  = h_in  + (size_t)N * 128;
    float* sg_in  = h_out + (size_t)N * 128;
    float* sg_out = sg_in + (size_t)N * 4;
    int*   row_in   = (int*)(sg_out + (size_t)N * 4);
    int*   row_out  = row_in  + (N + 1);
    int*   fill_in  = row_out + (N + 1);
    int*   fill_out = fill_in + (N + 1);
    int*   idx_in   = fill_out + (N + 1);
    int*   idx_out  = idx_in + E;

    const size_t need = ((size_t)(idx_out + E) - (size_t)d_ws);

    float* out = (float*)d_out;
    dim3 blk(256);

    sgcn_node<<<dim3((N + TN - 1) / TN), blk, 0, stream>>>(
        x, W_loop, b_loop, W_loop_g, b_loop_g,
        W_in, W_in_g, b_in_g, W_out, W_out_g, b_out_g,
        h_in, h_out, sg_in, sg_out, out, N);

    if (need <= ws_size) {
        // CSR build + atomic-free gather
        sgcn_zero<<<dim3((2 * (N + 1) + 255) / 256), blk, 0, stream>>>(fill_in, 2 * (N + 1));
        sgcn_hist<<<dim3((E + 255) / 256), blk, 0, stream>>>(ei, fill_in, fill_out, E);
        sgcn_scan<<<dim3(2), dim3(1024), 0, stream>>>(fill_in, row_in, fill_out, row_out, N);
        sgcn_fill<<<dim3((E + 255) / 256), blk, 0, stream>>>(ei, lab, fill_in, idx_in, fill_out, idx_out, E);
        sgcn_gather<<<dim3((N * 64 + 255) / 256), blk, 0, stream>>>(
            h_in, h_out, sg_in, sg_out, row_in, idx_in, row_out, idx_out,
            b_in, b_out, out, N);
    } else {
        sgcn_scatter<<<dim3(2048), blk, 0, stream>>>(
            h_in, h_out, sg_in, sg_out, ei, lab, b_in, b_out, out, E);
        const long total4 = (long)N * 128 / 4;
        sgcn_relu<<<dim3((unsigned)((total4 + 255) / 256)), blk, 0, stream>>>(out, total4);
    }
}

// Round 4
// 448.115 us; speedup vs baseline: 2.5811x; 1.4895x over previous
//
#include <hip/hip_runtime.h>
#include <math.h>

#define TN 64

__device__ __forceinline__ float sigmoidf_(float v) {
    return 1.f / (1.f + __expf(-v));
}

template <typename StoreF>
__device__ __forceinline__ void gemm_tile(
    const float* __restrict__ W, const float xs[TN][132],
    int ri, int ci, StoreF store)
{
    float acc[8][4];
    #pragma unroll
    for (int j = 0; j < 8; ++j)
        acc[j][0] = acc[j][1] = acc[j][2] = acc[j][3] = 0.f;
    #pragma unroll 4
    for (int k = 0; k < 128; ++k) {
        const float4 wv = *(const float4*)(W + k * 128 + ci);
        #pragma unroll
        for (int j = 0; j < 8; ++j) {
            const float xv = xs[ri + j][k];
            acc[j][0] = fmaf(xv, wv.x, acc[j][0]);
            acc[j][1] = fmaf(xv, wv.y, acc[j][1]);
            acc[j][2] = fmaf(xv, wv.z, acc[j][2]);
            acc[j][3] = fmaf(xv, wv.w, acc[j][3]);
        }
    }
    #pragma unroll
    for (int j = 0; j < 8; ++j)
        store(j, acc[j][0], acc[j][1], acc[j][2], acc[j][3]);
}

// Phase 1: per-node transforms (h_in, h_out, gates, x_loop into out).
__global__ __launch_bounds__(256) void sgcn_node(
    const float* __restrict__ x,
    const float* __restrict__ W_loop, const float* __restrict__ b_loop,
    const float* __restrict__ W_loop_g, const float* __restrict__ b_loop_g,
    const float* __restrict__ W_in, const float* __restrict__ W_in_g, const float* __restrict__ b_in_g,
    const float* __restrict__ W_out, const float* __restrict__ W_out_g, const float* __restrict__ b_out_g,
    float* __restrict__ h_in, float* __restrict__ h_out,
    float* __restrict__ sg_in, float* __restrict__ sg_out,
    float* __restrict__ out, int N)
{
    __shared__ float xs[TN][132];
    __shared__ float gls[TN];
    const int tid = threadIdx.x;
    const int n0 = blockIdx.x * TN;

    for (int i = tid * 4; i < TN * 128; i += 256 * 4) {
        const int row = i >> 7;
        const int col = i & 127;
        float4 v = make_float4(0.f, 0.f, 0.f, 0.f);
        if (n0 + row < N) v = *(const float4*)(x + (size_t)(n0 + row) * 128 + col);
        *(float4*)&xs[row][col] = v;
    }
    __syncthreads();

    if (tid < TN) {
        float gl = 0.f, gi = 0.f, go = 0.f;
        #pragma unroll 4
        for (int k = 0; k < 128; ++k) {
            const float xv = xs[tid][k];
            gl = fmaf(xv, W_loop_g[k], gl);
            gi = fmaf(xv, W_in_g[k], gi);
            go = fmaf(xv, W_out_g[k], go);
        }
        gls[tid] = sigmoidf_(gl + b_loop_g[0]);
        const int n = n0 + tid;
        if (n < N) {
            #pragma unroll
            for (int l = 0; l < 4; ++l) {
                sg_in[(size_t)n * 4 + l]  = sigmoidf_(gi + b_in_g[l]);
                sg_out[(size_t)n * 4 + l] = sigmoidf_(go + b_out_g[l]);
            }
        }
    }
    __syncthreads();

    const int ci = (tid & 31) * 4;
    const int ri = (tid >> 5) * 8;

    gemm_tile(W_in, xs, ri, ci,
        [&](int j, float a0, float a1, float a2, float a3) {
            const int n = n0 + ri + j;
            if (n < N)
                *(float4*)(h_in + (size_t)n * 128 + ci) = make_float4(a0, a1, a2, a3);
        });

    gemm_tile(W_out, xs, ri, ci,
        [&](int j, float a0, float a1, float a2, float a3) {
            const int n = n0 + ri + j;
            if (n < N)
                *(float4*)(h_out + (size_t)n * 128 + ci) = make_float4(a0, a1, a2, a3);
        });

    {
        const float4 bl = *(const float4*)(b_loop + ci);
        gemm_tile(W_loop, xs, ri, ci,
            [&](int j, float a0, float a1, float a2, float a3) {
                const int n = n0 + ri + j;
                if (n < N) {
                    const float g = gls[ri + j];
                    *(float4*)(out + (size_t)n * 128 + ci) =
                        make_float4(g * (a0 + bl.x), g * (a1 + bl.y),
                                    g * (a2 + bl.z), g * (a3 + bl.w));
                }
            });
    }
}

// ---------- CSR build ----------
__global__ __launch_bounds__(256) void sgcn_zero(int* __restrict__ p, int n)
{
    const int i = blockIdx.x * blockDim.x + threadIdx.x;
    if (i < n) p[i] = 0;
}

// cnt is concatenated: cnt[0..N) = in-degree (keyed by dst), cnt[N..2N) = out-degree (keyed by src)
__global__ __launch_bounds__(256) void sgcn_hist(
    const int* __restrict__ ei, int* __restrict__ cnt, int N, int E)
{
    const int e = blockIdx.x * blockDim.x + threadIdx.x;
    if (e < E) {
        atomicAdd(cnt + ei[E + e], 1);       // in-direction keyed by dst
        atomicAdd(cnt + N + ei[e], 1);       // out-direction keyed by src
    }
}

// Hierarchical scan, step 1: per-block (1024-element) sums.
__global__ __launch_bounds__(256) void scan_partial(
    const int* __restrict__ cnt, int* __restrict__ bsum, int M)
{
    const int t = threadIdx.x;
    const int base = blockIdx.x * 1024 + t * 4;
    int s = 0;
    if (base + 3 < M) {
        const int4 q = *(const int4*)(cnt + base);
        s = q.x + q.y + q.z + q.w;
    } else {
        for (int i = 0; i < 4; ++i) if (base + i < M) s += cnt[base + i];
    }
    #pragma unroll
    for (int off = 32; off; off >>= 1) s += __shfl_down(s, off, 64);
    __shared__ int red[4];
    if ((t & 63) == 0) red[t >> 6] = s;
    __syncthreads();
    if (t == 0) bsum[blockIdx.x] = red[0] + red[1] + red[2] + red[3];
}

// step 2: exclusive scan of block sums (B <= 256*K), single block.
__global__ __launch_bounds__(256) void scan_bsums(int* __restrict__ bsum, int B)
{
    __shared__ int part[256];
    const int t = threadIdx.x;
    const int K = (B + 255) / 256;
    const int lo = t * K;
    const int hi = min(lo + K, B);
    int s = 0;
    for (int i = lo; i < hi; ++i) s += bsum[i];
    part[t] = s;
    __syncthreads();
    for (int off = 1; off < 256; off <<= 1) {
        const int v = (t >= off) ? part[t - off] : 0;
        __syncthreads();
        part[t] += v;
        __syncthreads();
    }
    int run = (t > 0) ? part[t - 1] : 0;
    for (int i = lo; i < hi; ++i) {
        const int c = bsum[i];
        bsum[i] = run;
        run += c;
    }
}

// step 3: finalize — exclusive prefix for every element; write row arrays + fill cursors.
__global__ __launch_bounds__(256) void scan_final(
    int* __restrict__ cnt, const int* __restrict__ bsum,
    int* __restrict__ row_in, int* __restrict__ row_out, int N, int E)
{
    const int t = threadIdx.x;
    const int base = blockIdx.x * 1024 + t * 4;
    const int M = 2 * N;
    int v0 = 0, v1 = 0, v2 = 0, v3 = 0;
    if (base + 3 < M) {
        const int4 q = *(const int4*)(cnt + base);
        v0 = q.x; v1 = q.y; v2 = q.z; v3 = q.w;
    } else {
        if (base     < M) v0 = cnt[base];
        if (base + 1 < M) v1 = cnt[base + 1];
        if (base + 2 < M) v2 = cnt[base + 2];
        if (base + 3 < M) v3 = cnt[base + 3];
    }
    const int s = v0 + v1 + v2 + v3;
    const int lane = t & 63;
    int inc = s;
    #pragma unroll
    for (int off = 1; off < 64; off <<= 1) {
        const int u = __shfl_up(inc, off, 64);
        if (lane >= off) inc += u;
    }
    __shared__ int wsum[4];
    if (lane == 63) wsum[t >> 6] = inc;
    __syncthreads();
    int wpre = 0;
    const int w = t >> 6;
    for (int i = 0; i < w; ++i) wpre += wsum[i];
    int run = bsum[blockIdx.x] + wpre + (inc - s);   // exclusive prefix
    const int vv[4] = {v0, v1, v2, v3};
    #pragma unroll
    for (int i = 0; i < 4; ++i) {
        const int g = base + i;
        if (g < M) {
            if (g < N) row_in[g] = run; else row_out[g - N] = run;
            cnt[g] = run;                             // becomes the fill cursor
            run += vv[i];
        }
    }
    if (blockIdx.x == 0 && t == 0) { row_in[N] = E; row_out[N] = 2 * E; }
}

__global__ __launch_bounds__(256) void sgcn_fill(
    const int* __restrict__ ei, const int* __restrict__ lab,
    int* __restrict__ fill, int* __restrict__ idx, int N, int E)
{
    const int e = blockIdx.x * blockDim.x + threadIdx.x;
    if (e < E) {
        const int s = ei[e];
        const int d = ei[E + e];
        const int l = lab[e];
        const int pi = atomicAdd(fill + d, 1);        // in [0, E)
        idx[pi] = s * 4 + l;                          // p>>2 = node, p&3 = label
        const int po = atomicAdd(fill + N + s, 1);    // in [E, 2E)
        idx[po] = d * 4 + l;
    }
}

// Phase 2 (CSR): one wave per node; gather both directions, add self-loop (already in out),
// relu, store. No atomics.
__global__ __launch_bounds__(256) void sgcn_gather(
    const float* __restrict__ h_in, const float* __restrict__ h_out,
    const float* __restrict__ sg_in, const float* __restrict__ sg_out,
    const int* __restrict__ row_in, const int* __restrict__ row_out,
    const int* __restrict__ idx,
    const float* __restrict__ b_in, const float* __restrict__ b_out,
    float* __restrict__ out, int N)
{
    const int lane = threadIdx.x & 63;
    const int node = (int)((blockIdx.x * (unsigned)blockDim.x + threadIdx.x) >> 6);
    if (node >= N) return;
    const int c = lane * 2;

    float2 acc = *(const float2*)(out + (size_t)node * 128 + c);

    int e0 = row_in[node], e1 = row_in[node + 1];
    for (int e = e0; e < e1; ++e) {
        const int p = idx[e];
        const float g = sg_in[p];
        const float2 hv = *(const float2*)(h_in + (size_t)(p >> 2) * 128 + c);
        const float2 bv = *(const float2*)(b_in + (p & 3) * 128 + c);
        acc.x = fmaf(g, hv.x + bv.x, acc.x);
        acc.y = fmaf(g, hv.y + bv.y, acc.y);
    }
    e0 = row_out[node]; e1 = row_out[node + 1];
    for (int e = e0; e < e1; ++e) {
        const int p = idx[e];
        const float g = sg_out[p];
        const float2 hv = *(const float2*)(h_out + (size_t)(p >> 2) * 128 + c);
        const float2 bv = *(const float2*)(b_out + (p & 3) * 128 + c);
        acc.x = fmaf(g, hv.x + bv.x, acc.x);
        acc.y = fmaf(g, hv.y + bv.y, acc.y);
    }
    *(float2*)(out + (size_t)node * 128 + c) =
        make_float2(fmaxf(acc.x, 0.f), fmaxf(acc.y, 0.f));
}

// ---------- fallback (round-2 proven path) ----------
__global__ __launch_bounds__(256) void sgcn_scatter(
    const float* __restrict__ h_in, const float* __restrict__ h_out,
    const float* __restrict__ sg_in, const float* __restrict__ sg_out,
    const int* __restrict__ ei, const int* __restrict__ lab,
    const float* __restrict__ b_in, const float* __restrict__ b_out,
    float* __restrict__ out, int E)
{
    const int lane = threadIdx.x & 63;
    const int wid = (blockIdx.x * blockDim.x + threadIdx.x) >> 6;
    const int nw = (gridDim.x * blockDim.x) >> 6;
    const int c = lane * 2;

    for (int e = wid; e < E; e += nw) {
        const int s = ei[e];
        const int d = ei[E + e];
        const int l = lab[e];
        {
            const float2 hv = *(const float2*)(h_in + (size_t)s * 128 + c);
            const float2 bv = *(const float2*)(b_in + l * 128 + c);
            const float g = sg_in[(size_t)s * 4 + l];
            atomicAdd(out + (size_t)d * 128 + c,     g * (hv.x + bv.x));
            atomicAdd(out + (size_t)d * 128 + c + 1, g * (hv.y + bv.y));
        }
        {
            const float2 hv = *(const float2*)(h_out + (size_t)d * 128 + c);
            const float2 bv = *(const float2*)(b_out + l * 128 + c);
            const float g = sg_out[(size_t)d * 4 + l];
            atomicAdd(out + (size_t)s * 128 + c,     g * (hv.x + bv.x));
            atomicAdd(out + (size_t)s * 128 + c + 1, g * (hv.y + bv.y));
        }
    }
}

__global__ __launch_bounds__(256) void sgcn_relu(float* __restrict__ out, long total4)
{
    const long i = (long)blockIdx.x * blockDim.x + threadIdx.x;
    if (i < total4) {
        float4 v = ((float4*)out)[i];
        v.x = fmaxf(v.x, 0.f); v.y = fmaxf(v.y, 0.f);
        v.z = fmaxf(v.z, 0.f); v.w = fmaxf(v.w, 0.f);
        ((float4*)out)[i] = v;
    }
}

extern "C" void kernel_launch(void* const* d_in, const int* in_sizes, int n_in,
                              void* d_out, int out_size, void* d_ws, size_t ws_size,
                              hipStream_t stream)
{
    const float* x        = (const float*)d_in[0];
    const int*   ei       = (const int*)d_in[1];
    const int*   lab      = (const int*)d_in[2];
    const float* W_loop   = (const float*)d_in[3];
    const float* b_loop   = (const float*)d_in[4];
    const float* W_loop_g = (const float*)d_in[5];
    const float* b_loop_g = (const float*)d_in[6];
    const float* W_in     = (const float*)d_in[7];
    const float* b_in     = (const float*)d_in[8];
    const float* W_in_g   = (const float*)d_in[9];
    const float* b_in_g   = (const float*)d_in[10];
    const float* W_out    = (const float*)d_in[11];
    const float* b_out    = (const float*)d_in[12];
    const float* W_out_g  = (const float*)d_in[13];
    const float* b_out_g  = (const float*)d_in[14];

    const int N = in_sizes[0] / 128;
    const int E = in_sizes[1] / 2;
    const int M = 2 * N;
    const int B = (M + 1023) / 1024;

    float* h_in   = (float*)d_ws;
    float* h_out  = h_in  + (size_t)N * 128;
    float* sg_in  = h_out + (size_t)N * 128;
    float* sg_out = sg_in + (size_t)N * 4;
    int*   row_in  = (int*)(sg_out + (size_t)N * 4);
    int*   row_out = row_in  + (N + 1);
    int*   cnt     = row_out + (N + 1);     // 2N: counts -> fill cursors
    int*   bsum    = cnt + M;               // B
    int*   idx     = bsum + ((B + 3) & ~3); // 2E
    const size_t need = ((size_t)(idx + 2 * (size_t)E) - (size_t)d_ws);

    float* out = (float*)d_out;
    dim3 blk(256);

    sgcn_node<<<dim3((N + TN - 1) / TN), blk, 0, stream>>>(
        x, W_loop, b_loop, W_loop_g, b_loop_g,
        W_in, W_in_g, b_in_g, W_out, W_out_g, b_out_g,
        h_in, h_out, sg_in, sg_out, out, N);

    if (need <= ws_size) {
        sgcn_zero<<<dim3((M + 255) / 256), blk, 0, stream>>>(cnt, M);
        sgcn_hist<<<dim3((E + 255) / 256), blk, 0, stream>>>(ei, cnt, N, E);
        scan_partial<<<dim3(B), blk, 0, stream>>>(cnt, bsum, M);
        scan_bsums<<<dim3(1), blk, 0, stream>>>(bsum, B);
        scan_final<<<dim3(B), blk, 0, stream>>>(cnt, bsum, row_in, row_out, N, E);
        sgcn_fill<<<dim3((E + 255) / 256), blk, 0, stream>>>(ei, lab, cnt, idx, N, E);
        sgcn_gather<<<dim3((N * 64 + 255) / 256), blk, 0, stream>>>(
            h_in, h_out, sg_in, sg_out, row_in, row_out, idx, b_in, b_out, out, N);
    } else {
        sgcn_scatter<<<dim3(2048), blk, 0, stream>>>(
            h_in, h_out, sg_in, sg_out, ei, lab, b_in, b_out, out, E);
        const long total4 = (long)N * 128 / 4;
        sgcn_relu<<<dim3((unsigned)((total4 + 255) / 256)), blk, 0, stream>>>(out, total4);
    }
}

// Round 5
// 365.685 us; speedup vs baseline: 3.1629x; 1.2254x over previous
//
#include <hip/hip_runtime.h>
#include <math.h>

typedef float  f32x4  __attribute__((ext_vector_type(4)));
typedef short  bf16x8 __attribute__((ext_vector_type(8)));
typedef unsigned short u16x8 __attribute__((ext_vector_type(8)));

#define XROW 136   // padded LDS row stride in bf16 elems (272 B): breaks 32-way bank conflict

__device__ __forceinline__ float sigmoidf_(float v) {
    return 1.f / (1.f + __expf(-v));
}
__device__ __forceinline__ unsigned short f2b(float f) {
    union { float f; unsigned u; } c; c.f = f;
    const unsigned r = c.u + 0x7FFF + ((c.u >> 16) & 1);   // round-to-nearest-even
    return (unsigned short)(r >> 16);
}
__device__ __forceinline__ float b2f(unsigned short u) {
    union { unsigned u; float f; } c; c.u = ((unsigned)u) << 16;
    return c.f;
}

// Prep: Wt[m][n][k] (bf16) = W_m[k][n], m in {0:in, 1:out, 2:loop}
__global__ __launch_bounds__(256) void conv_w(
    const float* __restrict__ Win, const float* __restrict__ Wout,
    const float* __restrict__ Wloop, unsigned short* __restrict__ Wt)
{
    const int t = blockIdx.x * 256 + threadIdx.x;
    if (t >= 3 * 16384) return;
    const int m = t >> 14;
    const int i = t & 16383;           // k*128 + n (coalesced read)
    const int k = i >> 7, n = i & 127;
    const float* W = (m == 0) ? Win : ((m == 1) ? Wout : Wloop);
    Wt[m * 16384 + n * 128 + k] = f2b(W[i]);
}

// Phase 1 (MFMA): 128 nodes/block, 4 waves, 32 nodes/wave.
// h_in/h_out written as bf16; self-loop (gated, biased) written fp32 into out.
__global__ __launch_bounds__(256) void sgcn_node_mfma(
    const float* __restrict__ x,
    const unsigned short* __restrict__ Wt,
    const float* __restrict__ b_loop,
    const float* __restrict__ W_loop_g, const float* __restrict__ b_loop_g,
    const float* __restrict__ W_in_g, const float* __restrict__ b_in_g,
    const float* __restrict__ W_out_g, const float* __restrict__ b_out_g,
    unsigned short* __restrict__ h_in, unsigned short* __restrict__ h_out,
    float* __restrict__ sg_in, float* __restrict__ sg_out,
    float* __restrict__ out, int N)
{
    __shared__ unsigned short xs[128 * XROW];   // ~34.8 KB
    __shared__ float gls[128];
    const int tid = threadIdx.x;
    const int n0 = blockIdx.x * 128;

    // stage x tile -> bf16 LDS; thread t: row t>>1, half (t&1)
    {
        const int row = tid >> 1;
        const int cb = (tid & 1) * 64;
        unsigned short* dst = &xs[row * XROW + cb];
        const int n = n0 + row;
        if (n < N) {
            const float* xr = x + (size_t)n * 128 + cb;
            #pragma unroll
            for (int i = 0; i < 64; i += 8) {
                const float4 v0 = *(const float4*)(xr + i);
                const float4 v1 = *(const float4*)(xr + i + 4);
                u16x8 pk;
                pk[0] = f2b(v0.x); pk[1] = f2b(v0.y); pk[2] = f2b(v0.z); pk[3] = f2b(v0.w);
                pk[4] = f2b(v1.x); pk[5] = f2b(v1.y); pk[6] = f2b(v1.z); pk[7] = f2b(v1.w);
                *(u16x8*)(dst + i) = pk;
            }
        } else {
            const u16x8 z = {0,0,0,0,0,0,0,0};
            #pragma unroll
            for (int i = 0; i < 64; i += 8) *(u16x8*)(dst + i) = z;
        }
    }
    __syncthreads();

    // gates: thread t<128 -> node n0+t (3 dots of K=128 from LDS)
    if (tid < 128) {
        const int n = n0 + tid;
        if (n < N) {
            float gl = 0.f, gi = 0.f, go = 0.f;
            const unsigned short* xr = &xs[tid * XROW];
            for (int kc = 0; kc < 128; kc += 8) {
                const u16x8 c = *(const u16x8*)(xr + kc);
                #pragma unroll
                for (int j = 0; j < 8; ++j) {
                    const float xv = b2f(c[j]);
                    gl = fmaf(xv, W_loop_g[kc + j], gl);
                    gi = fmaf(xv, W_in_g[kc + j], gi);
                    go = fmaf(xv, W_out_g[kc + j], go);
                }
            }
            gls[tid] = sigmoidf_(gl + b_loop_g[0]);
            #pragma unroll
            for (int l = 0; l < 4; ++l) {
                sg_in[(size_t)n * 4 + l]  = sigmoidf_(gi + b_in_g[l]);
                sg_out[(size_t)n * 4 + l] = sigmoidf_(go + b_out_g[l]);
            }
        } else {
            gls[tid] = 0.f;
        }
    }
    __syncthreads();

    const int w  = tid >> 6;     // wave 0..3
    const int l  = tid & 63;
    const int lr = l & 15;       // A row / B col / C col within 16
    const int lk = l >> 4;       // k-chunk group (8 k each)
    const int rbase = w * 32;    // wave's first node row in tile

    const unsigned short* a0p = &xs[(rbase + lr) * XROW + lk * 8];
    const unsigned short* a1p = &xs[(rbase + 16 + lr) * XROW + lk * 8];

    for (int ph = 0; ph < 3; ++ph) {
        const unsigned short* Wp = Wt + (size_t)ph * 16384;
        f32x4 acc[2][8];
        #pragma unroll
        for (int p = 0; p < 2; ++p)
            #pragma unroll
            for (int nt = 0; nt < 8; ++nt)
                acc[p][nt] = (f32x4){0.f, 0.f, 0.f, 0.f};

        #pragma unroll
        for (int ks = 0; ks < 4; ++ks) {
            const bf16x8 a0 = *(const bf16x8*)(a0p + ks * 32);
            const bf16x8 a1 = *(const bf16x8*)(a1p + ks * 32);
            #pragma unroll
            for (int nt = 0; nt < 8; ++nt) {
                const bf16x8 b = *(const bf16x8*)(Wp + (nt * 16 + lr) * 128 + ks * 32 + lk * 8);
                acc[0][nt] = __builtin_amdgcn_mfma_f32_16x16x32_bf16(a0, b, acc[0][nt], 0, 0, 0);
                acc[1][nt] = __builtin_amdgcn_mfma_f32_16x16x32_bf16(a1, b, acc[1][nt], 0, 0, 0);
            }
        }

        if (ph < 2) {
            unsigned short* hp = (ph == 0) ? h_in : h_out;
            #pragma unroll
            for (int p = 0; p < 2; ++p)
                #pragma unroll
                for (int r = 0; r < 4; ++r) {
                    const int node = n0 + rbase + p * 16 + lk * 4 + r;
                    if (node < N) {
                        unsigned short* row = hp + (size_t)node * 128 + lr;
                        #pragma unroll
                        for (int nt = 0; nt < 8; ++nt)
                            row[nt * 16] = f2b(acc[p][nt][r]);
                    }
                }
        } else {
            #pragma unroll
            for (int p = 0; p < 2; ++p)
                #pragma unroll
                for (int r = 0; r < 4; ++r) {
                    const int node = n0 + rbase + p * 16 + lk * 4 + r;
                    if (node < N) {
                        const float g = gls[rbase + p * 16 + lk * 4 + r];
                        float* row = out + (size_t)node * 128 + lr;
                        #pragma unroll
                        for (int nt = 0; nt < 8; ++nt)
                            row[nt * 16] = g * (acc[p][nt][r] + b_loop[nt * 16 + lr]);
                    }
                }
        }
    }
}

// ---------- CSR build ----------
__global__ __launch_bounds__(256) void sgcn_zero(int* __restrict__ p, int n)
{
    const int i = blockIdx.x * blockDim.x + threadIdx.x;
    if (i < n) p[i] = 0;
}

__global__ __launch_bounds__(256) void sgcn_hist(
    const int* __restrict__ ei, int* __restrict__ cnt, int N, int E)
{
    const int e = blockIdx.x * blockDim.x + threadIdx.x;
    if (e < E) {
        atomicAdd(cnt + ei[E + e], 1);
        atomicAdd(cnt + N + ei[e], 1);
    }
}

__global__ __launch_bounds__(256) void scan_partial(
    const int* __restrict__ cnt, int* __restrict__ bsum, int M)
{
    const int t = threadIdx.x;
    const int base = blockIdx.x * 1024 + t * 4;
    int s = 0;
    if (base + 3 < M) {
        const int4 q = *(const int4*)(cnt + base);
        s = q.x + q.y + q.z + q.w;
    } else {
        for (int i = 0; i < 4; ++i) if (base + i < M) s += cnt[base + i];
    }
    #pragma unroll
    for (int off = 32; off; off >>= 1) s += __shfl_down(s, off, 64);
    __shared__ int red[4];
    if ((t & 63) == 0) red[t >> 6] = s;
    __syncthreads();
    if (t == 0) bsum[blockIdx.x] = red[0] + red[1] + red[2] + red[3];
}

__global__ __launch_bounds__(256) void scan_bsums(int* __restrict__ bsum, int B)
{
    __shared__ int part[256];
    const int t = threadIdx.x;
    const int K = (B + 255) / 256;
    const int lo = t * K;
    const int hi = min(lo + K, B);
    int s = 0;
    for (int i = lo; i < hi; ++i) s += bsum[i];
    part[t] = s;
    __syncthreads();
    for (int off = 1; off < 256; off <<= 1) {
        const int v = (t >= off) ? part[t - off] : 0;
        __syncthreads();
        part[t] += v;
        __syncthreads();
    }
    int run = (t > 0) ? part[t - 1] : 0;
    for (int i = lo; i < hi; ++i) {
        const int c = bsum[i];
        bsum[i] = run;
        run += c;
    }
}

__global__ __launch_bounds__(256) void scan_final(
    int* __restrict__ cnt, const int* __restrict__ bsum,
    int* __restrict__ row_in, int* __restrict__ row_out, int N, int E)
{
    const int t = threadIdx.x;
    const int base = blockIdx.x * 1024 + t * 4;
    const int M = 2 * N;
    int v0 = 0, v1 = 0, v2 = 0, v3 = 0;
    if (base + 3 < M) {
        const int4 q = *(const int4*)(cnt + base);
        v0 = q.x; v1 = q.y; v2 = q.z; v3 = q.w;
    } else {
        if (base     < M) v0 = cnt[base];
        if (base + 1 < M) v1 = cnt[base + 1];
        if (base + 2 < M) v2 = cnt[base + 2];
        if (base + 3 < M) v3 = cnt[base + 3];
    }
    const int s = v0 + v1 + v2 + v3;
    const int lane = t & 63;
    int inc = s;
    #pragma unroll
    for (int off = 1; off < 64; off <<= 1) {
        const int u = __shfl_up(inc, off, 64);
        if (lane >= off) inc += u;
    }
    __shared__ int wsum[4];
    if (lane == 63) wsum[t >> 6] = inc;
    __syncthreads();
    int wpre = 0;
    const int w = t >> 6;
    for (int i = 0; i < w; ++i) wpre += wsum[i];
    int run = bsum[blockIdx.x] + wpre + (inc - s);
    const int vv[4] = {v0, v1, v2, v3};
    #pragma unroll
    for (int i = 0; i < 4; ++i) {
        const int g = base + i;
        if (g < M) {
            if (g < N) row_in[g] = run; else row_out[g - N] = run;
            cnt[g] = run;
            run += vv[i];
        }
    }
    if (blockIdx.x == 0 && t == 0) { row_in[N] = E; row_out[N] = 2 * E; }
}

__global__ __launch_bounds__(256) void sgcn_fill(
    const int* __restrict__ ei, const int* __restrict__ lab,
    int* __restrict__ fill, int* __restrict__ idx, int N, int E)
{
    const int e = blockIdx.x * blockDim.x + threadIdx.x;
    if (e < E) {
        const int s = ei[e];
        const int d = ei[E + e];
        const int l = lab[e];
        const int pi = atomicAdd(fill + d, 1);
        idx[pi] = s * 4 + l;
        const int po = atomicAdd(fill + N + s, 1);
        idx[po] = d * 4 + l;
    }
}

// Phase 2 (CSR): one wave per node, bf16 h gathers (256 B/edge), no atomics.
__global__ __launch_bounds__(256) void sgcn_gather(
    const unsigned short* __restrict__ h_in, const unsigned short* __restrict__ h_out,
    const float* __restrict__ sg_in, const float* __restrict__ sg_out,
    const int* __restrict__ row_in, const int* __restrict__ row_out,
    const int* __restrict__ idx,
    const float* __restrict__ b_in, const float* __restrict__ b_out,
    float* __restrict__ out, int N)
{
    const int lane = threadIdx.x & 63;
    const int node = (int)((blockIdx.x * (unsigned)blockDim.x + threadIdx.x) >> 6);
    if (node >= N) return;
    const int c = lane * 2;

    float2 acc = *(const float2*)(out + (size_t)node * 128 + c);

    int e0 = row_in[node], e1 = row_in[node + 1];
    for (int e = e0; e < e1; ++e) {
        const int p = idx[e];
        const float g = sg_in[p];
        const ushort2 hv = *(const ushort2*)(h_in + (size_t)(p >> 2) * 128 + c);
        const float2 bv = *(const float2*)(b_in + (p & 3) * 128 + c);
        acc.x = fmaf(g, b2f(hv.x) + bv.x, acc.x);
        acc.y = fmaf(g, b2f(hv.y) + bv.y, acc.y);
    }
    e0 = row_out[node]; e1 = row_out[node + 1];
    for (int e = e0; e < e1; ++e) {
        const int p = idx[e];
        const float g = sg_out[p];
        const ushort2 hv = *(const ushort2*)(h_out + (size_t)(p >> 2) * 128 + c);
        const float2 bv = *(const float2*)(b_out + (p & 3) * 128 + c);
        acc.x = fmaf(g, b2f(hv.x) + bv.x, acc.x);
        acc.y = fmaf(g, b2f(hv.y) + bv.y, acc.y);
    }
    *(float2*)(out + (size_t)node * 128 + c) =
        make_float2(fmaxf(acc.x, 0.f), fmaxf(acc.y, 0.f));
}

// ---------- fallback (atomic path) ----------
__global__ __launch_bounds__(256) void sgcn_scatter(
    const unsigned short* __restrict__ h_in, const unsigned short* __restrict__ h_out,
    const float* __restrict__ sg_in, const float* __restrict__ sg_out,
    const int* __restrict__ ei, const int* __restrict__ lab,
    const float* __restrict__ b_in, const float* __restrict__ b_out,
    float* __restrict__ out, int E)
{
    const int lane = threadIdx.x & 63;
    const int wid = (blockIdx.x * blockDim.x + threadIdx.x) >> 6;
    const int nw = (gridDim.x * blockDim.x) >> 6;
    const int c = lane * 2;

    for (int e = wid; e < E; e += nw) {
        const int s = ei[e];
        const int d = ei[E + e];
        const int l = lab[e];
        {
            const ushort2 hv = *(const ushort2*)(h_in + (size_t)s * 128 + c);
            const float2 bv = *(const float2*)(b_in + l * 128 + c);
            const float g = sg_in[(size_t)s * 4 + l];
            atomicAdd(out + (size_t)d * 128 + c,     g * (b2f(hv.x) + bv.x));
            atomicAdd(out + (size_t)d * 128 + c + 1, g * (b2f(hv.y) + bv.y));
        }
        {
            const ushort2 hv = *(const ushort2*)(h_out + (size_t)d * 128 + c);
            const float2 bv = *(const float2*)(b_out + l * 128 + c);
            const float g = sg_out[(size_t)d * 4 + l];
            atomicAdd(out + (size_t)s * 128 + c,     g * (b2f(hv.x) + bv.x));
            atomicAdd(out + (size_t)s * 128 + c + 1, g * (b2f(hv.y) + bv.y));
        }
    }
}

__global__ __launch_bounds__(256) void sgcn_relu(float* __restrict__ out, long total4)
{
    const long i = (long)blockIdx.x * blockDim.x + threadIdx.x;
    if (i < total4) {
        float4 v = ((float4*)out)[i];
        v.x = fmaxf(v.x, 0.f); v.y = fmaxf(v.y, 0.f);
        v.z = fmaxf(v.z, 0.f); v.w = fmaxf(v.w, 0.f);
        ((float4*)out)[i] = v;
    }
}

extern "C" void kernel_launch(void* const* d_in, const int* in_sizes, int n_in,
                              void* d_out, int out_size, void* d_ws, size_t ws_size,
                              hipStream_t stream)
{
    const float* x        = (const float*)d_in[0];
    const int*   ei       = (const int*)d_in[1];
    const int*   lab      = (const int*)d_in[2];
    const float* W_loop   = (const float*)d_in[3];
    const float* b_loop   = (const float*)d_in[4];
    const float* W_loop_g = (const float*)d_in[5];
    const float* b_loop_g = (const float*)d_in[6];
    const float* W_in     = (const float*)d_in[7];
    const float* b_in     = (const float*)d_in[8];
    const float* W_in_g   = (const float*)d_in[9];
    const float* b_in_g   = (const float*)d_in[10];
    const float* W_out    = (const float*)d_in[11];
    const float* b_out    = (const float*)d_in[12];
    const float* W_out_g  = (const float*)d_in[13];
    const float* b_out_g  = (const float*)d_in[14];

    const int N = in_sizes[0] / 128;
    const int E = in_sizes[1] / 2;
    const int M = 2 * N;
    const int B = (M + 1023) / 1024;

    unsigned short* h_in  = (unsigned short*)d_ws;            // N*128 bf16
    unsigned short* h_out = h_in + (size_t)N * 128;           // N*128 bf16
    float* sg_in  = (float*)(h_out + (size_t)N * 128);        // N*4
    float* sg_out = sg_in + (size_t)N * 4;                    // N*4
    unsigned short* Wt = (unsigned short*)(sg_out + (size_t)N * 4);  // 3*16384 bf16
    int* row_in  = (int*)(Wt + 3 * 16384);                    // N+1
    int* row_out = row_in + (N + 1);                          // N+1
    int* cnt     = row_out + (N + 1);                         // 2N
    int* bsum    = cnt + M;                                   // B
    int* idx     = bsum + ((B + 3) & ~3);                     // 2E
    const size_t need = ((size_t)(idx + 2 * (size_t)E) - (size_t)d_ws);

    float* out = (float*)d_out;
    dim3 blk(256);

    conv_w<<<dim3(192), blk, 0, stream>>>(W_in, W_out, W_loop, Wt);

    sgcn_node_mfma<<<dim3((N + 127) / 128), blk, 0, stream>>>(
        x, Wt, b_loop, W_loop_g, b_loop_g, W_in_g, b_in_g, W_out_g, b_out_g,
        h_in, h_out, sg_in, sg_out, out, N);

    if (need <= ws_size) {
        sgcn_zero<<<dim3((M + 255) / 256), blk, 0, stream>>>(cnt, M);
        sgcn_hist<<<dim3((E + 255) / 256), blk, 0, stream>>>(ei, cnt, N, E);
        scan_partial<<<dim3(B), blk, 0, stream>>>(cnt, bsum, M);
        scan_bsums<<<dim3(1), blk, 0, stream>>>(bsum, B);
        scan_final<<<dim3(B), blk, 0, stream>>>(cnt, bsum, row_in, row_out, N, E);
        sgcn_fill<<<dim3((E + 255) / 256), blk, 0, stream>>>(ei, lab, cnt, idx, N, E);
        sgcn_gather<<<dim3((N * 64 + 255) / 256), blk, 0, stream>>>(
            h_in, h_out, sg_in, sg_out, row_in, row_out, idx, b_in, b_out, out, N);
    } else {
        sgcn_scatter<<<dim3(2048), blk, 0, stream>>>(
            h_in, h_out, sg_in, sg_out, ei, lab, b_in, b_out, out, E);
        const long total4 = (long)N * 128 / 4;
        sgcn_relu<<<dim3((unsigned)((total4 + 255) / 256)), blk, 0, stream>>>(out, total4);
    }
}

// Round 8
// 322.413 us; speedup vs baseline: 3.5874x; 1.1342x over previous
//
#include <hip/hip_runtime.h>
#include <math.h>

typedef float  f32x4  __attribute__((ext_vector_type(4)));
typedef short  bf16x8 __attribute__((ext_vector_type(8)));
typedef unsigned short u16x8 __attribute__((ext_vector_type(8)));

#define XROW 136   // padded LDS row stride in bf16 elems (272 B): breaks 32-way bank conflict

__device__ __forceinline__ float sigmoidf_(float v) {
    return 1.f / (1.f + __expf(-v));
}
__device__ __forceinline__ unsigned short f2b(float f) {
    union { float f; unsigned u; } c; c.f = f;
    const unsigned r = c.u + 0x7FFF + ((c.u >> 16) & 1);   // round-to-nearest-even
    return (unsigned short)(r >> 16);
}
__device__ __forceinline__ float b2f(unsigned short u) {
    union { unsigned u; float f; } c; c.u = ((unsigned)u) << 16;
    return c.f;
}

// Prep: Wt[m][n][k] (bf16) = W_m[k][n], m in {0:in, 1:out, 2:loop}
__global__ __launch_bounds__(256) void conv_w(
    const float* __restrict__ Win, const float* __restrict__ Wout,
    const float* __restrict__ Wloop, unsigned short* __restrict__ Wt)
{
    const int t = blockIdx.x * 256 + threadIdx.x;
    if (t >= 3 * 16384) return;
    const int m = t >> 14;
    const int i = t & 16383;           // k*128 + n (coalesced read)
    const int k = i >> 7, n = i & 127;
    const float* W = (m == 0) ? Win : ((m == 1) ? Wout : Wloop);
    Wt[m * 16384 + n * 128 + k] = f2b(W[i]);
}

// Phase 1 (MFMA): 128 nodes/block, 4 waves, 32 nodes/wave.
__global__ __launch_bounds__(256) void sgcn_node_mfma(
    const float* __restrict__ x,
    const unsigned short* __restrict__ Wt,
    const float* __restrict__ b_loop,
    const float* __restrict__ W_loop_g, const float* __restrict__ b_loop_g,
    const float* __restrict__ W_in_g, const float* __restrict__ b_in_g,
    const float* __restrict__ W_out_g, const float* __restrict__ b_out_g,
    unsigned short* __restrict__ h_in, unsigned short* __restrict__ h_out,
    float* __restrict__ sg_in, float* __restrict__ sg_out,
    float* __restrict__ out, int N)
{
    __shared__ unsigned short xs[128 * XROW];   // ~34.8 KB
    __shared__ float gls[128];
    const int tid = threadIdx.x;
    const int n0 = blockIdx.x * 128;

    {
        const int row = tid >> 1;
        const int cb = (tid & 1) * 64;
        unsigned short* dst = &xs[row * XROW + cb];
        const int n = n0 + row;
        if (n < N) {
            const float* xr = x + (size_t)n * 128 + cb;
            #pragma unroll
            for (int i = 0; i < 64; i += 8) {
                const float4 v0 = *(const float4*)(xr + i);
                const float4 v1 = *(const float4*)(xr + i + 4);
                u16x8 pk;
                pk[0] = f2b(v0.x); pk[1] = f2b(v0.y); pk[2] = f2b(v0.z); pk[3] = f2b(v0.w);
                pk[4] = f2b(v1.x); pk[5] = f2b(v1.y); pk[6] = f2b(v1.z); pk[7] = f2b(v1.w);
                *(u16x8*)(dst + i) = pk;
            }
        } else {
            const u16x8 z = {0,0,0,0,0,0,0,0};
            #pragma unroll
            for (int i = 0; i < 64; i += 8) *(u16x8*)(dst + i) = z;
        }
    }
    __syncthreads();

    if (tid < 128) {
        const int n = n0 + tid;
        if (n < N) {
            float gl = 0.f, gi = 0.f, go = 0.f;
            const unsigned short* xr = &xs[tid * XROW];
            for (int kc = 0; kc < 128; kc += 8) {
                const u16x8 c = *(const u16x8*)(xr + kc);
                #pragma unroll
                for (int j = 0; j < 8; ++j) {
                    const float xv = b2f(c[j]);
                    gl = fmaf(xv, W_loop_g[kc + j], gl);
                    gi = fmaf(xv, W_in_g[kc + j], gi);
                    go = fmaf(xv, W_out_g[kc + j], go);
                }
            }
            gls[tid] = sigmoidf_(gl + b_loop_g[0]);
            #pragma unroll
            for (int l = 0; l < 4; ++l) {
                sg_in[(size_t)n * 4 + l]  = sigmoidf_(gi + b_in_g[l]);
                sg_out[(size_t)n * 4 + l] = sigmoidf_(go + b_out_g[l]);
            }
        } else {
            gls[tid] = 0.f;
        }
    }
    __syncthreads();

    const int w  = tid >> 6;
    const int l  = tid & 63;
    const int lr = l & 15;
    const int lk = l >> 4;
    const int rbase = w * 32;

    const unsigned short* a0p = &xs[(rbase + lr) * XROW + lk * 8];
    const unsigned short* a1p = &xs[(rbase + 16 + lr) * XROW + lk * 8];

    for (int ph = 0; ph < 3; ++ph) {
        const unsigned short* Wp = Wt + (size_t)ph * 16384;
        f32x4 acc[2][8];
        #pragma unroll
        for (int p = 0; p < 2; ++p)
            #pragma unroll
            for (int nt = 0; nt < 8; ++nt)
                acc[p][nt] = (f32x4){0.f, 0.f, 0.f, 0.f};

        #pragma unroll
        for (int ks = 0; ks < 4; ++ks) {
            const bf16x8 a0 = *(const bf16x8*)(a0p + ks * 32);
            const bf16x8 a1 = *(const bf16x8*)(a1p + ks * 32);
            #pragma unroll
            for (int nt = 0; nt < 8; ++nt) {
                const bf16x8 b = *(const bf16x8*)(Wp + (nt * 16 + lr) * 128 + ks * 32 + lk * 8);
                acc[0][nt] = __builtin_amdgcn_mfma_f32_16x16x32_bf16(a0, b, acc[0][nt], 0, 0, 0);
                acc[1][nt] = __builtin_amdgcn_mfma_f32_16x16x32_bf16(a1, b, acc[1][nt], 0, 0, 0);
            }
        }

        if (ph < 2) {
            unsigned short* hp = (ph == 0) ? h_in : h_out;
            #pragma unroll
            for (int p = 0; p < 2; ++p)
                #pragma unroll
                for (int r = 0; r < 4; ++r) {
                    const int node = n0 + rbase + p * 16 + lk * 4 + r;
                    if (node < N) {
                        unsigned short* row = hp + (size_t)node * 128 + lr;
                        #pragma unroll
                        for (int nt = 0; nt < 8; ++nt)
                            row[nt * 16] = f2b(acc[p][nt][r]);
                    }
                }
        } else {
            #pragma unroll
            for (int p = 0; p < 2; ++p)
                #pragma unroll
                for (int r = 0; r < 4; ++r) {
                    const int node = n0 + rbase + p * 16 + lk * 4 + r;
                    if (node < N) {
                        const float g = gls[rbase + p * 16 + lk * 4 + r];
                        float* row = out + (size_t)node * 128 + lr;
                        #pragma unroll
                        for (int nt = 0; nt < 8; ++nt)
                            row[nt * 16] = g * (acc[p][nt][r] + b_loop[nt * 16 + lr]);
                    }
                }
        }
    }
}

// ---------- CSR build ----------
__global__ __launch_bounds__(256) void sgcn_zero(int* __restrict__ p, int n)
{
    const int i = blockIdx.x * blockDim.x + threadIdx.x;
    if (i < n) p[i] = 0;
}

__global__ __launch_bounds__(256) void sgcn_hist(
    const int* __restrict__ ei, int* __restrict__ cnt, int N, int E)
{
    const int e = blockIdx.x * blockDim.x + threadIdx.x;
    if (e < E) {
        atomicAdd(cnt + ei[E + e], 1);
        atomicAdd(cnt + N + ei[e], 1);
    }
}

__global__ __launch_bounds__(256) void scan_partial(
    const int* __restrict__ cnt, int* __restrict__ bsum, int M)
{
    const int t = threadIdx.x;
    const int base = blockIdx.x * 1024 + t * 4;
    int s = 0;
    if (base + 3 < M) {
        const int4 q = *(const int4*)(cnt + base);
        s = q.x + q.y + q.z + q.w;
    } else {
        for (int i = 0; i < 4; ++i) if (base + i < M) s += cnt[base + i];
    }
    #pragma unroll
    for (int off = 32; off; off >>= 1) s += __shfl_down(s, off, 64);
    __shared__ int red[4];
    if ((t & 63) == 0) red[t >> 6] = s;
    __syncthreads();
    if (t == 0) bsum[blockIdx.x] = red[0] + red[1] + red[2] + red[3];
}

__global__ __launch_bounds__(256) void scan_bsums(int* __restrict__ bsum, int B)
{
    __shared__ int part[256];
    const int t = threadIdx.x;
    const int K = (B + 255) / 256;
    const int lo = t * K;
    const int hi = min(lo + K, B);
    int s = 0;
    for (int i = lo; i < hi; ++i) s += bsum[i];
    part[t] = s;
    __syncthreads();
    for (int off = 1; off < 256; off <<= 1) {
        const int v = (t >= off) ? part[t - off] : 0;
        __syncthreads();
        part[t] += v;
        __syncthreads();
    }
    int run = (t > 0) ? part[t - 1] : 0;
    for (int i = lo; i < hi; ++i) {
        const int c = bsum[i];
        bsum[i] = run;
        run += c;
    }
}

__global__ __launch_bounds__(256) void scan_final(
    int* __restrict__ cnt, const int* __restrict__ bsum,
    int* __restrict__ row_in, int* __restrict__ row_out, int N, int E)
{
    const int t = threadIdx.x;
    const int base = blockIdx.x * 1024 + t * 4;
    const int M = 2 * N;
    int v0 = 0, v1 = 0, v2 = 0, v3 = 0;
    if (base + 3 < M) {
        const int4 q = *(const int4*)(cnt + base);
        v0 = q.x; v1 = q.y; v2 = q.z; v3 = q.w;
    } else {
        if (base     < M) v0 = cnt[base];
        if (base + 1 < M) v1 = cnt[base + 1];
        if (base + 2 < M) v2 = cnt[base + 2];
        if (base + 3 < M) v3 = cnt[base + 3];
    }
    const int s = v0 + v1 + v2 + v3;
    const int lane = t & 63;
    int inc = s;
    #pragma unroll
    for (int off = 1; off < 64; off <<= 1) {
        const int u = __shfl_up(inc, off, 64);
        if (lane >= off) inc += u;
    }
    __shared__ int wsum[4];
    if (lane == 63) wsum[t >> 6] = inc;
    __syncthreads();
    int wpre = 0;
    const int w = t >> 6;
    for (int i = 0; i < w; ++i) wpre += wsum[i];
    int run = bsum[blockIdx.x] + wpre + (inc - s);
    const int vv[4] = {v0, v1, v2, v3};
    #pragma unroll
    for (int i = 0; i < 4; ++i) {
        const int g = base + i;
        if (g < M) {
            if (g < N) row_in[g] = run; else row_out[g - N] = run;
            cnt[g] = run;
            run += vv[i];
        }
    }
    if (blockIdx.x == 0 && t == 0) { row_in[N] = E; row_out[N] = 2 * E; }
}

__global__ __launch_bounds__(256) void sgcn_fill(
    const int* __restrict__ ei, const int* __restrict__ lab,
    int* __restrict__ fill, int* __restrict__ idx, int N, int E)
{
    const int e = blockIdx.x * blockDim.x + threadIdx.x;
    if (e < E) {
        const int s = ei[e];
        const int d = ei[E + e];
        const int l = lab[e];
        const int pi = atomicAdd(fill + d, 1);
        idx[pi] = s * 4 + l;
        const int po = atomicAdd(fill + N + s, 1);
        idx[po] = d * 4 + l;
    }
}

// Phase 2 (CSR): one wave per node, 4 edge-groups of 16 lanes => 4 gathers in flight.
// Label-bias factored out: sum_e g*(h+b_l) = sum_e g*h + sum_l (sum gates_l) * b_l.
__global__ __launch_bounds__(256) void sgcn_gather4(
    const unsigned short* __restrict__ h_in, const unsigned short* __restrict__ h_out,
    const float* __restrict__ sg_in, const float* __restrict__ sg_out,
    const int* __restrict__ row_in, const int* __restrict__ row_out,
    const int* __restrict__ idx,
    const float* __restrict__ b_in, const float* __restrict__ b_out,
    float* __restrict__ out, int N)
{
    const int lane = threadIdx.x & 63;
    const int node = (int)((blockIdx.x * (unsigned)blockDim.x + threadIdx.x) >> 6);
    if (node >= N) return;
    const int sub = lane >> 4;      // edge group 0..3
    const int sl  = lane & 15;      // 16 lanes x 8 cols = 128 cols
    const int cb  = sl * 8;

    float acc[8];
    #pragma unroll
    for (int j = 0; j < 8; ++j) acc[j] = 0.f;
    float gi0 = 0.f, gi1 = 0.f, gi2 = 0.f, gi3 = 0.f;
    float go0 = 0.f, go1 = 0.f, go2 = 0.f, go3 = 0.f;

    {
        const int e1 = row_in[node + 1];
        for (int e = row_in[node] + sub; e < e1; e += 4) {
            const int p = idx[e];
            const float g = sg_in[p];
            const u16x8 hv = *(const u16x8*)(h_in + (size_t)(p >> 2) * 128 + cb);
            const int l = p & 3;
            gi0 += (l == 0) ? g : 0.f;
            gi1 += (l == 1) ? g : 0.f;
            gi2 += (l == 2) ? g : 0.f;
            gi3 += (l == 3) ? g : 0.f;
            #pragma unroll
            for (int j = 0; j < 8; ++j) acc[j] = fmaf(g, b2f(hv[j]), acc[j]);
        }
    }
    {
        const int e1 = row_out[node + 1];
        for (int e = row_out[node] + sub; e < e1; e += 4) {
            const int p = idx[e];
            const float g = sg_out[p];
            const u16x8 hv = *(const u16x8*)(h_out + (size_t)(p >> 2) * 128 + cb);
            const int l = p & 3;
            go0 += (l == 0) ? g : 0.f;
            go1 += (l == 1) ? g : 0.f;
            go2 += (l == 2) ? g : 0.f;
            go3 += (l == 3) ? g : 0.f;
            #pragma unroll
            for (int j = 0; j < 8; ++j) acc[j] = fmaf(g, b2f(hv[j]), acc[j]);
        }
    }

    // combine the 4 edge groups (lanes l, l^16, l^32, l^48 share the same cols)
    #pragma unroll
    for (int j = 0; j < 8; ++j) {
        acc[j] += __shfl_xor(acc[j], 16, 64);
        acc[j] += __shfl_xor(acc[j], 32, 64);
    }
    gi0 += __shfl_xor(gi0, 16, 64); gi0 += __shfl_xor(gi0, 32, 64);
    gi1 += __shfl_xor(gi1, 16, 64); gi1 += __shfl_xor(gi1, 32, 64);
    gi2 += __shfl_xor(gi2, 16, 64); gi2 += __shfl_xor(gi2, 32, 64);
    gi3 += __shfl_xor(gi3, 16, 64); gi3 += __shfl_xor(gi3, 32, 64);
    go0 += __shfl_xor(go0, 16, 64); go0 += __shfl_xor(go0, 32, 64);
    go1 += __shfl_xor(go1, 16, 64); go1 += __shfl_xor(go1, 32, 64);
    go2 += __shfl_xor(go2, 16, 64); go2 += __shfl_xor(go2, 32, 64);
    go3 += __shfl_xor(go3, 16, 64); go3 += __shfl_xor(go3, 32, 64);

    if (sub == 0) {
        const float gis[4] = {gi0, gi1, gi2, gi3};
        const float gos[4] = {go0, go1, go2, go3};
        #pragma unroll
        for (int l = 0; l < 4; ++l) {
            const float4 bi0 = *(const float4*)(b_in + l * 128 + cb);
            const float4 bi1 = *(const float4*)(b_in + l * 128 + cb + 4);
            const float4 bo0 = *(const float4*)(b_out + l * 128 + cb);
            const float4 bo1 = *(const float4*)(b_out + l * 128 + cb + 4);
            acc[0] = fmaf(gis[l], bi0.x, fmaf(gos[l], bo0.x, acc[0]));
            acc[1] = fmaf(gis[l], bi0.y, fmaf(gos[l], bo0.y, acc[1]));
            acc[2] = fmaf(gis[l], bi0.z, fmaf(gos[l], bo0.z, acc[2]));
            acc[3] = fmaf(gis[l], bi0.w, fmaf(gos[l], bo0.w, acc[3]));
            acc[4] = fmaf(gis[l], bi1.x, fmaf(gos[l], bo1.x, acc[4]));
            acc[5] = fmaf(gis[l], bi1.y, fmaf(gos[l], bo1.y, acc[5]));
            acc[6] = fmaf(gis[l], bi1.z, fmaf(gos[l], bo1.z, acc[6]));
            acc[7] = fmaf(gis[l], bi1.w, fmaf(gos[l], bo1.w, acc[7]));
        }
        float* orow = out + (size_t)node * 128 + cb;
        float4 o0 = *(const float4*)orow;
        float4 o1 = *(const float4*)(orow + 4);
        o0.x = fmaxf(o0.x + acc[0], 0.f); o0.y = fmaxf(o0.y + acc[1], 0.f);
        o0.z = fmaxf(o0.z + acc[2], 0.f); o0.w = fmaxf(o0.w + acc[3], 0.f);
        o1.x = fmaxf(o1.x + acc[4], 0.f); o1.y = fmaxf(o1.y + acc[5], 0.f);
        o1.z = fmaxf(o1.z + acc[6], 0.f); o1.w = fmaxf(o1.w + acc[7], 0.f);
        *(float4*)orow = o0;
        *(float4*)(orow + 4) = o1;
    }
}

// ---------- fallback (atomic path) ----------
__global__ __launch_bounds__(256) void sgcn_scatter(
    const unsigned short* __restrict__ h_in, const unsigned short* __restrict__ h_out,
    const float* __restrict__ sg_in, const float* __restrict__ sg_out,
    const int* __restrict__ ei, const int* __restrict__ lab,
    const float* __restrict__ b_in, const float* __restrict__ b_out,
    float* __restrict__ out, int E)
{
    const int lane = threadIdx.x & 63;
    const int wid = (blockIdx.x * blockDim.x + threadIdx.x) >> 6;
    const int nw = (gridDim.x * blockDim.x) >> 6;
    const int c = lane * 2;

    for (int e = wid; e < E; e += nw) {
        const int s = ei[e];
        const int d = ei[E + e];
        const int l = lab[e];
        {
            const ushort2 hv = *(const ushort2*)(h_in + (size_t)s * 128 + c);
            const float2 bv = *(const float2*)(b_in + l * 128 + c);
            const float g = sg_in[(size_t)s * 4 + l];
            atomicAdd(out + (size_t)d * 128 + c,     g * (b2f(hv.x) + bv.x));
            atomicAdd(out + (size_t)d * 128 + c + 1, g * (b2f(hv.y) + bv.y));
        }
        {
            const ushort2 hv = *(const ushort2*)(h_out + (size_t)d * 128 + c);
            const float2 bv = *(const float2*)(b_out + l * 128 + c);
            const float g = sg_out[(size_t)d * 4 + l];
            atomicAdd(out + (size_t)s * 128 + c,     g * (b2f(hv.x) + bv.x));
            atomicAdd(out + (size_t)s * 128 + c + 1, g * (b2f(hv.y) + bv.y));
        }
    }
}

__global__ __launch_bounds__(256) void sgcn_relu(float* __restrict__ out, long total4)
{
    const long i = (long)blockIdx.x * blockDim.x + threadIdx.x;
    if (i < total4) {
        float4 v = ((float4*)out)[i];
        v.x = fmaxf(v.x, 0.f); v.y = fmaxf(v.y, 0.f);
        v.z = fmaxf(v.z, 0.f); v.w = fmaxf(v.w, 0.f);
        ((float4*)out)[i] = v;
    }
}

extern "C" void kernel_launch(void* const* d_in, const int* in_sizes, int n_in,
                              void* d_out, int out_size, void* d_ws, size_t ws_size,
                              hipStream_t stream)
{
    const float* x        = (const float*)d_in[0];
    const int*   ei       = (const int*)d_in[1];
    const int*   lab      = (const int*)d_in[2];
    const float* W_loop   = (const float*)d_in[3];
    const float* b_loop   = (const float*)d_in[4];
    const float* W_loop_g = (const float*)d_in[5];
    const float* b_loop_g = (const float*)d_in[6];
    const float* W_in     = (const float*)d_in[7];
    const float* b_in     = (const float*)d_in[8];
    const float* W_in_g   = (const float*)d_in[9];
    const float* b_in_g   = (const float*)d_in[10];
    const float* W_out    = (const float*)d_in[11];
    const float* b_out    = (const float*)d_in[12];
    const float* W_out_g  = (const float*)d_in[13];
    const float* b_out_g  = (const float*)d_in[14];

    const int N = in_sizes[0] / 128;
    const int E = in_sizes[1] / 2;
    const int M = 2 * N;
    const int B = (M + 1023) / 1024;

    unsigned short* h_in  = (unsigned short*)d_ws;            // N*128 bf16
    unsigned short* h_out = h_in + (size_t)N * 128;           // N*128 bf16
    float* sg_in  = (float*)(h_out + (size_t)N * 128);        // N*4
    float* sg_out = sg_in + (size_t)N * 4;                    // N*4
    unsigned short* Wt = (unsigned short*)(sg_out + (size_t)N * 4);  // 3*16384 bf16
    int* row_in  = (int*)(Wt + 3 * 16384);                    // N+1
    int* row_out = row_in + (N + 1);                          // N+1
    int* cnt     = row_out + (N + 1);                         // 2N
    int* bsum    = cnt + M;                                   // B
    int* idx     = bsum + ((B + 3) & ~3);                     // 2E
    const size_t need = ((size_t)(idx + 2 * (size_t)E) - (size_t)d_ws);

    float* out = (float*)d_out;
    dim3 blk(256);

    conv_w<<<dim3(192), blk, 0, stream>>>(W_in, W_out, W_loop, Wt);

    sgcn_node_mfma<<<dim3((N + 127) / 128), blk, 0, stream>>>(
        x, Wt, b_loop, W_loop_g, b_loop_g, W_in_g, b_in_g, W_out_g, b_out_g,
        h_in, h_out, sg_in, sg_out, out, N);

    if (need <= ws_size) {
        sgcn_zero<<<dim3((M + 255) / 256), blk, 0, stream>>>(cnt, M);
        sgcn_hist<<<dim3((E + 255) / 256), blk, 0, stream>>>(ei, cnt, N, E);
        scan_partial<<<dim3(B), blk, 0, stream>>>(cnt, bsum, M);
        scan_bsums<<<dim3(1), blk, 0, stream>>>(bsum, B);
        scan_final<<<dim3(B), blk, 0, stream>>>(cnt, bsum, row_in, row_out, N, E);
        sgcn_fill<<<dim3((E + 255) / 256), blk, 0, stream>>>(ei, lab, cnt, idx, N, E);
        sgcn_gather4<<<dim3((N * 64 + 255) / 256), blk, 0, stream>>>(
            h_in, h_out, sg_in, sg_out, row_in, row_out, idx, b_in, b_out, out, N);
    } else {
        sgcn_scatter<<<dim3(2048), blk, 0, stream>>>(
            h_in, h_out, sg_in, sg_out, ei, lab, b_in, b_out, out, E);
        const long total4 = (long)N * 128 / 4;
        sgcn_relu<<<dim3((unsigned)((total4 + 255) / 256)), blk, 0, stream>>>(out, total4);
    }
}